// Round 6
// baseline (21.353 us; speedup 1.0000x reference)
//
#include <hip/hip_runtime.h>
#include <cmath>

constexpr int Bn = 2, Hn = 256, Wn = 256, Cn = 2;
constexpr int QW = Wn * Cn;   // 512 "columns" per image = (w,c) pairs
constexpr int NG = 16;        // i-groups (each covers 16 i's)
constexpr int NJ = 4;         // j's per thread: jl + {0,64,128,192}

// ---------------------------------------------------------------------------
// Pass 1: fused transpose + precompute.
// Reads img/fmap [B, H, QW] coalesced, computes per element:
//   x0 = clip(fmap + i, 0, 255),  p = img * sin(pi*x0)/pi
// and writes x0t/pt as [B, QW, H] (coalesced via 32x32 LDS tile).
// ---------------------------------------------------------------------------
__global__ __launch_bounds__(256) void prep_kernel(
    const float* __restrict__ img, const float* __restrict__ fmap,
    float* __restrict__ x0t, float* __restrict__ pt)
{
    const float INV_PI = 0x1.45f306p-2f;  // float32(1/pi)
    __shared__ float tlx[32][33];         // +1 pad: conflict-free transpose
    __shared__ float tlp[32][33];

    const int bidx = blockIdx.x;      // 2 b * 16 q-tiles * 8 i-tiles = 256
    const int b  = bidx >> 7;
    const int tl = bidx & 127;
    const int q0 = (tl & 15) * 32;    // q-tile origin (QW/32 = 16)
    const int i0 = (tl >> 4) * 32;    // i-tile origin (Hn/32 = 8)
    const int tx = threadIdx.x & 31;
    const int ty = threadIdx.x >> 5;  // 0..7

    const size_t bin = (size_t)b * Hn * QW;
#pragma unroll
    for (int r = 0; r < 4; ++r) {
        const int i = i0 + ty + 8 * r;
        const int q = q0 + tx;
        const size_t off = bin + (size_t)i * QW + q;   // coalesced along q
        const float f  = fmap[off];
        float x0 = fminf(fmaxf(f + (float)i, 0.0f), 255.0f);
        const float n  = rintf(x0);
        const float rr = x0 - n;                        // [-0.5, 0.5]
        float sp = __builtin_amdgcn_sinf(0.5f * rr) * INV_PI; // sin(pi*rr)/pi
        if (((int)n) & 1) sp = -sp;                     // -> sin(pi*x0)/pi
        tlx[ty + 8 * r][tx] = x0;
        tlp[ty + 8 * r][tx] = img[off] * sp;
    }
    __syncthreads();

    const size_t bout = (size_t)b * QW * Hn;
#pragma unroll
    for (int r = 0; r < 4; ++r) {
        const int q = q0 + ty + 8 * r;
        const int i = i0 + tx;
        const size_t off = bout + (size_t)q * Hn + i;   // coalesced along i
        x0t[off] = tlx[tx][ty + 8 * r];
        pt [off] = tlp[tx][ty + 8 * r];
    }
}

// ---------------------------------------------------------------------------
// Pass 2: main compute. Block (b,w) stages its contiguous 2x2KB slice of
// x0t/pt ([c][i] order), then thread (ig, jl) sums 16 i's for 4 j's, 2 c's.
// Grouped reciprocal: one v_rcp per 4 terms. BIAS=2^-31 guards d==0
// (x0 integer there => p==0 => term is exactly 0; any nonzero |d| >= 2^-24
// so d+BIAS is never 0 and never denormal).
// ---------------------------------------------------------------------------
__global__ __launch_bounds__(1024, 4) void sinc_main_kernel(
    const float* __restrict__ x0t, const float* __restrict__ pt,
    float* __restrict__ out)
{
    const float BIAS = 0x1p-31f;

    __shared__ __align__(16) float4 shx[128];   // [c][i] : idx = c*64 + i/4
    __shared__ __align__(16) float4 shp[128];
    __shared__ float sh_acc[NG][Hn * Cn];       // 32 KB partials

    const int bw = blockIdx.x;
    const int b  = bw >> 8;
    const int w  = bw & 255;
    const int t  = threadIdx.x;

    // Stage: 2 KB per array, fully coalesced (128 float4 each).
    const size_t base = ((size_t)b * Wn + w) * (Cn * Hn);  // q = 2w
    if (t < 128)       shx[t]       = ((const float4*)(x0t + base))[t];
    else if (t < 256)  shp[t - 128] = ((const float4*)(pt  + base))[t - 128];
    __syncthreads();

    const int ig = t >> 6;
    const int jl = t & 63;

    float acc[NJ][2];
#pragma unroll
    for (int jj = 0; jj < NJ; ++jj) { acc[jj][0] = 0.0f; acc[jj][1] = 0.0f; }

#pragma unroll
    for (int k = 0; k < 4; ++k) {             // 16 i's = 4 float4 per channel
        const float4 xv0 = shx[ig * 4 + k];        // c = 0
        const float4 pv0 = shp[ig * 4 + k];
        const float4 xv1 = shx[64 + ig * 4 + k];   // c = 1
        const float4 pv1 = shp[64 + ig * 4 + k];
#pragma unroll
        for (int jj = 0; jj < NJ; ++jj) {
            const float J = (float)(jl + 64 * jj);
            {   // channel 0: one rcp for 4 terms
                const float d0 = (xv0.x - J) + BIAS;
                const float d1 = (xv0.y - J) + BIAS;
                const float d2 = (xv0.z - J) + BIAS;
                const float d3 = (xv0.w - J) + BIAS;
                const float m01 = d0 * d1, m23 = d2 * d3;
                const float r   = __builtin_amdgcn_rcpf(m01 * m23);
                const float r01 = m23 * r, r23 = m01 * r;
                acc[jj][0] = fmaf(pv0.x, d1 * r01, acc[jj][0]);
                acc[jj][0] = fmaf(pv0.y, d0 * r01, acc[jj][0]);
                acc[jj][0] = fmaf(pv0.z, d3 * r23, acc[jj][0]);
                acc[jj][0] = fmaf(pv0.w, d2 * r23, acc[jj][0]);
            }
            {   // channel 1
                const float d0 = (xv1.x - J) + BIAS;
                const float d1 = (xv1.y - J) + BIAS;
                const float d2 = (xv1.z - J) + BIAS;
                const float d3 = (xv1.w - J) + BIAS;
                const float m01 = d0 * d1, m23 = d2 * d3;
                const float r   = __builtin_amdgcn_rcpf(m01 * m23);
                const float r01 = m23 * r, r23 = m01 * r;
                acc[jj][1] = fmaf(pv1.x, d1 * r01, acc[jj][1]);
                acc[jj][1] = fmaf(pv1.y, d0 * r01, acc[jj][1]);
                acc[jj][1] = fmaf(pv1.z, d3 * r23, acc[jj][1]);
                acc[jj][1] = fmaf(pv1.w, d2 * r23, acc[jj][1]);
            }
        }
    }

    // Partials -> LDS, reduce across the 16 i-groups.
#pragma unroll
    for (int jj = 0; jj < NJ; ++jj) {
        const int j = jl + 64 * jj;
        *(float2*)&sh_acc[ig][j * 2] = make_float2(acc[jj][0], acc[jj][1]);
    }
    __syncthreads();

    if (t < Hn * Cn) {
        float a = 0.0f;
#pragma unroll
        for (int g = 0; g < NG; ++g) a += sh_acc[g][t];
        const int j = t >> 1, c = t & 1;
        const float sgn = (j & 1) ? -1.0f : 1.0f;   // (-1)^j folded back in
        out[(((size_t)b * Hn + j) * Wn + w) * Cn + c] = sgn * a;
    }
}

extern "C" void kernel_launch(void* const* d_in, const int* in_sizes, int n_in,
                              void* d_out, int out_size, void* d_ws, size_t ws_size,
                              hipStream_t stream)
{
    (void)in_sizes; (void)n_in; (void)out_size; (void)ws_size;
    const float* img  = (const float*)d_in[0];
    const float* fmap = (const float*)d_in[1];
    float* out = (float*)d_out;

    float* x0t = (float*)d_ws;                       // 1 MB
    float* pt  = (float*)d_ws + (size_t)Bn * QW * Hn; // +1 MB

    prep_kernel<<<256, 256, 0, stream>>>(img, fmap, x0t, pt);
    sinc_main_kernel<<<Bn * Wn, 1024, 0, stream>>>(x0t, pt, out);
}

// Round 7
// 15.956 us; speedup vs baseline: 1.3382x; 1.3382x over previous
//
#include <hip/hip_runtime.h>
#include <cmath>

constexpr int Bn = 2, Hn = 256, Wn = 256, Cn = 2;
constexpr int NG = 16;   // i-groups (16 i's = 4 quads each)
constexpr int NJ = 4;    // j's per thread: jl + {0,64,128,192}

__global__ __launch_bounds__(1024, 4) void sinc_main_kernel(
    const float* __restrict__ img, const float* __restrict__ fmap,
    float* __restrict__ out)
{
    const float INV_PI = 0x1.45f306p-2f;  // float32(1/pi)

    __shared__ __align__(16) float sh_x[Cn][Hn];  // x0, [c][i] for quad reads
    __shared__ __align__(16) float sh_p[Cn][Hn];  // img * sin(pi*x0)/pi
    __shared__ float sh_acc[NG][Hn * Cn];         // 32 KB partials

    const int bw = blockIdx.x;
    const int b  = bw >> 8;
    const int w  = bw & 255;
    const int t  = threadIdx.x;

    // ---- Stage: thread t < 512 owns (i = t&255, c = t>>8). ----
    if (t < Hn * Cn) {
        const int i = t & 255, c = t >> 8;
        const size_t off = (((size_t)b * Hn + i) * Wn + w) * Cn + c;
        const float f = fmap[off];
        float x0 = fminf(fmaxf(f + (float)i, 0.0f), 255.0f);
        const float n = rintf(x0);
        const float r = x0 - n;                         // [-0.5, 0.5]
        float sp = __builtin_amdgcn_sinf(0.5f * r) * INV_PI; // sin(pi*x0)/pi mag
        if (((int)n) & 1) sp = -sp;
        const float p = img[off] * sp;
        // Nudge: p==0 ⟺ this row contributes nothing (x0 at integer / clip).
        // Shift x0 so d = x0 - J is never exactly 0; identity Σp/d is exact
        // for any nonzero d when p==0, so this introduces zero error.
        if (p == 0.0f) x0 += 0x1p-15f;                  // exact (≥2 ulp of 255)
        sh_x[c][i] = x0;
        sh_p[c][i] = p;
    }
    __syncthreads();

    // ---- Compute: thread (ig, jl): i in [ig*16, ig*16+16), 4 j's, 2 c's. ----
    const int ig = t >> 6;
    const int jl = t & 63;

    float acc[NJ][2];
#pragma unroll
    for (int jj = 0; jj < NJ; ++jj) { acc[jj][0] = 0.0f; acc[jj][1] = 0.0f; }

    const float4* qx = (const float4*)sh_x;   // index: c*64 + i/4
    const float4* qp = (const float4*)sh_p;

#pragma unroll
    for (int q = 0; q < 4; ++q) {             // 4 quads of 4 consecutive i's
        const int iq = ig * 4 + q;
        const float4 x0q = qx[iq],      p0q = qp[iq];        // c = 0
        const float4 x1q = qx[64 + iq], p1q = qp[64 + iq];   // c = 1
#pragma unroll
        for (int jj = 0; jj < NJ; ++jj) {
            const float J = (float)(jl + 64 * jj);
            {   // channel 0: Σ_{4 i's} p/d as N/D, one rcp
                const float d0 = x0q.x - J, d1 = x0q.y - J;
                const float d2 = x0q.z - J, d3 = x0q.w - J;
                const float m01 = d0 * d1, m23 = d2 * d3;
                const float n01 = fmaf(p0q.x, d1, p0q.y * d0);
                const float n23 = fmaf(p0q.z, d3, p0q.w * d2);
                const float Nv  = fmaf(n01, m23, n23 * m01);
                const float Dv  = m01 * m23;
                acc[jj][0] = fmaf(Nv, __builtin_amdgcn_rcpf(Dv), acc[jj][0]);
            }
            {   // channel 1
                const float d0 = x1q.x - J, d1 = x1q.y - J;
                const float d2 = x1q.z - J, d3 = x1q.w - J;
                const float m01 = d0 * d1, m23 = d2 * d3;
                const float n01 = fmaf(p1q.x, d1, p1q.y * d0);
                const float n23 = fmaf(p1q.z, d3, p1q.w * d2);
                const float Nv  = fmaf(n01, m23, n23 * m01);
                const float Dv  = m01 * m23;
                acc[jj][1] = fmaf(Nv, __builtin_amdgcn_rcpf(Dv), acc[jj][1]);
            }
        }
    }

    // ---- Partials -> LDS, reduce across the 16 i-groups. ----
#pragma unroll
    for (int jj = 0; jj < NJ; ++jj) {
        const int j = jl + 64 * jj;
        *(float2*)&sh_acc[ig][j * 2] = make_float2(acc[jj][0], acc[jj][1]);
    }
    __syncthreads();

    if (t < Hn * Cn) {
        float a = 0.0f;
#pragma unroll
        for (int g = 0; g < NG; ++g) a += sh_acc[g][t];
        const int j = t >> 1, c = t & 1;
        const float sgn = (j & 1) ? -1.0f : 1.0f;   // (-1)^j folded back in
        out[(((size_t)b * Hn + j) * Wn + w) * Cn + c] = sgn * a;
    }
}

extern "C" void kernel_launch(void* const* d_in, const int* in_sizes, int n_in,
                              void* d_out, int out_size, void* d_ws, size_t ws_size,
                              hipStream_t stream)
{
    (void)in_sizes; (void)n_in; (void)out_size; (void)d_ws; (void)ws_size;
    const float* img  = (const float*)d_in[0];
    const float* fmap = (const float*)d_in[1];
    float* out = (float*)d_out;
    sinc_main_kernel<<<Bn * Wn, 1024, 0, stream>>>(img, fmap, out);
}